// Round 4
// baseline (250.061 us; speedup 1.0000x reference)
//
#include <hip/hip_runtime.h>
#include <hip/hip_bf16.h>
#include <cstdint>
#include <cstddef>

typedef __bf16 bf16;
typedef __bf16 bf16x8 __attribute__((ext_vector_type(8)));
typedef __bf16 bf16x4 __attribute__((ext_vector_type(4)));
typedef __bf16 bf16x2 __attribute__((ext_vector_type(2)));
typedef float f32x4 __attribute__((ext_vector_type(4)));
typedef float f32x16 __attribute__((ext_vector_type(16)));
typedef unsigned int u32;
typedef u32 u32x4 __attribute__((ext_vector_type(4)));

#define LDS_CAST(p) (__attribute__((address_space(3))) void*)(p)
#define GLB_CAST(p) (const __attribute__((address_space(1))) void*)(p)
#define MFMA32(a, b, c) __builtin_amdgcn_mfma_f32_32x32x16_bf16(a, b, c, 0, 0, 0)

#if __has_builtin(__builtin_amdgcn_exp2f)
#define EXPF(x) __builtin_amdgcn_exp2f(x)
#define QK_SCALE 0.18033688011112042f  /* 0.125 * log2(e) */
#else
#define EXPF(x) __expf(x)
#define QK_SCALE 0.125f
#endif

static constexpr int BATCH = 8;
static constexpr int NSEQ  = 1024;
static constexpr int CDIM  = 768;
static constexpr int NH    = 12;
static constexpr int HD    = 64;
static constexpr int MTOT  = BATCH * NSEQ;   // 8192
static constexpr int NC3   = 3 * CDIM;       // 2304

__device__ inline u32 pkbf(float a, float b) {
    bf16x2 t = { (bf16)a, (bf16)b };
    return __builtin_bit_cast(u32, t);
}

// ---------------- cast fp32 -> bf16 (vectorized) ----------------
__global__ void cast_kernel(const float* __restrict__ src, bf16* __restrict__ dst, int n4) {
    int i = blockIdx.x * blockDim.x + threadIdx.x;
    if (i < n4) {
        float4 v = ((const float4*)src)[i];
        bf16x4 o = { (bf16)v.x, (bf16)v.y, (bf16)v.z, (bf16)v.w };
        ((bf16x4*)dst)[i] = o;
    }
}

// ------------- transpose-cast: dst[n][k] = (bf16)src[k][n] -------------
__global__ void tcast_kernel(const float* __restrict__ src, bf16* __restrict__ dst,
                             int K, int N) {
    int k = blockIdx.x * blockDim.x + threadIdx.x;
    int n = blockIdx.y;
    if (k < K) dst[(size_t)n * K + k] = (bf16)src[(size_t)k * N + n];
}

// ---------------- GEMM v2: C[M,Nd] = A[M,K] @ Bt[Nd,K]^T + bias ----------------
// 32x32x16 MFMA, chunk-major LDS (conflict-free b128 reads), dbuf single-sync K-loop.
// TM=128: 4 waves in 2x2 (64x64 quadrant each). TM=64: 4 waves side-by-side (64x32 each).
// MODE 0: fp32 out (proj). MODE 1: scatter q/k->[B,H,N,D] (q pre-scaled), v->[B,H,D,N].
template <int MODE, int TM>
__global__ __launch_bounds__(256) void gemm_kernel(
    const bf16* __restrict__ A, const bf16* __restrict__ Bt,
    const float* __restrict__ bias, float* __restrict__ outf,
    bf16* __restrict__ q, bf16* __restrict__ kk, bf16* __restrict__ v,
    int Ndim, int K)
{
    constexpr int TU = (TM == 128) ? 2 : 1;   // N sub-tiles per wave
    constexpr int AI = TM / 64;               // A staging instrs per thread
    __shared__ alignas(16) bf16 sA[2][TM * 32];
    __shared__ alignas(16) bf16 sB[2][128 * 32];
    const int tid  = threadIdx.x;
    const int lane = tid & 63;
    const int w    = tid >> 6;
    const int h    = lane >> 5;
    const int l32  = lane & 31;
    const int wm   = (TM == 128) ? (w >> 1) * 64 : 0;
    const int wn   = (TM == 128) ? (w & 1) * 64 : w * 32;
    const int tm   = blockIdx.y * TM;
    const int tn   = blockIdx.x * 128;

    const bf16* gA = A  + (size_t)tm * K;
    const bf16* gB = Bt + (size_t)tn * K;

    // chunk-major LDS: slot s = c*ROWS + r holds global (row r, k-chunk c) 16B.
    auto stage = [&](int k0, int buf) {
#pragma unroll
        for (int i = 0; i < AI; i++) {
            int s = (w * AI + i) * 64 + lane;
            int r = s % TM, c = s / TM;
            __builtin_amdgcn_global_load_lds(GLB_CAST(gA + (size_t)r * K + k0 + c * 8),
                LDS_CAST(&sA[buf][(w * AI + i) * 512]), 16, 0, 0);
        }
#pragma unroll
        for (int i = 0; i < 2; i++) {
            int s = (w * 2 + i) * 64 + lane;
            int r = s & 127, c = s >> 7;
            __builtin_amdgcn_global_load_lds(GLB_CAST(gB + (size_t)r * K + k0 + c * 8),
                LDS_CAST(&sB[buf][(w * 2 + i) * 512]), 16, 0, 0);
        }
    };

    f32x16 acc[2][TU];
#pragma unroll
    for (int t = 0; t < 2; t++)
#pragma unroll
        for (int u = 0; u < TU; u++)
#pragma unroll
            for (int i = 0; i < 16; i++) acc[t][u][i] = 0.f;

    const int NK = K / 32;
    stage(0, 0);
    for (int kt = 0; kt < NK; kt++) {
        const int cur = kt & 1;
        __syncthreads();                          // drains cur-buf loads (in flight since last iter)
        if (kt + 1 < NK) stage((kt + 1) * 32, cur ^ 1);  // FIX: element offset, not tile index
        const bf16* sAc = sA[cur];
        const bf16* sBc = sB[cur];

        bf16x8 af[2][2], bfr[TU][2];
#pragma unroll
        for (int t = 0; t < 2; t++)
#pragma unroll
            for (int kc = 0; kc < 2; kc++)
                af[t][kc] = *(const bf16x8*)(sAc + ((kc * 2 + h) * TM + wm + t * 32 + l32) * 8);
#pragma unroll
        for (int u = 0; u < TU; u++)
#pragma unroll
            for (int kc = 0; kc < 2; kc++)
                bfr[u][kc] = *(const bf16x8*)(sBc + ((kc * 2 + h) * 128 + wn + u * 32 + l32) * 8);
#pragma unroll
        for (int kc = 0; kc < 2; kc++)
#pragma unroll
            for (int t = 0; t < 2; t++)
#pragma unroll
                for (int u = 0; u < TU; u++)
                    acc[t][u] = MFMA32(af[t][kc], bfr[u][kc], acc[t][u]);
    }

    // C/D 32x32 layout: col n = l32, row m_local = (r&3) + 8*(r>>2) + 4*h  [verified in attn]
    if (MODE == 0) {
#pragma unroll
        for (int t = 0; t < 2; t++) {
            int mrow = tm + wm + t * 32 + 4 * h;
#pragma unroll
            for (int u = 0; u < TU; u++) {
                int col = tn + wn + u * 32 + l32;
                float bv = bias[col];
                float* op = outf + (size_t)mrow * Ndim + col;
#pragma unroll
                for (int r = 0; r < 16; r++) {
                    int rl = (r & 3) + 8 * (r >> 2);
                    op[(size_t)rl * Ndim] = acc[t][u][r] + bv;
                }
            }
        }
    } else {
        const int region = tn / 768;           // 0=q, 1=k, 2=v (uniform per block)
        const int rem0 = tn - region * 768 + wn;
#pragma unroll
        for (int t = 0; t < 2; t++) {
            int mrow = tm + wm + t * 32 + 4 * h;
            int b   = mrow >> 10;
            int nsb = mrow & 1023;
#pragma unroll
            for (int u = 0; u < TU; u++) {
                int rem = rem0 + u * 32 + l32;
                int hd = rem >> 6, d = rem & 63;
                float bv = bias[region * 768 + rem];
                if (region == 2) {
                    // v^T [B,H,D,N]; reg groups of 4 are consecutive ns -> bf16x4
                    bf16* vp = v + ((size_t)(b * NH + hd) * HD + d) * NSEQ + nsb;
#pragma unroll
                    for (int g = 0; g < 4; g++) {
                        bf16x4 t4 = { (bf16)(acc[t][u][4 * g + 0] + bv),
                                      (bf16)(acc[t][u][4 * g + 1] + bv),
                                      (bf16)(acc[t][u][4 * g + 2] + bv),
                                      (bf16)(acc[t][u][4 * g + 3] + bv) };
                        *(bf16x4*)(vp + 8 * g) = t4;
                    }
                } else {
                    bf16* qp = (region == 0 ? q : kk) + ((size_t)(b * NH + hd) * NSEQ + nsb) * HD + d;
                    const float sc = (region == 0) ? (float)QK_SCALE : 1.0f;
#pragma unroll
                    for (int r = 0; r < 16; r++) {
                        int rl = (r & 3) + 8 * (r >> 2);
                        qp[(size_t)rl * HD] = (bf16)((acc[t][u][r] + bv) * sc);
                    }
                }
            }
        }
    }
}

// ---------------- flash attention: S^T/O^T formulation, 32x32 MFMA (unchanged) ----------------
__global__ __launch_bounds__(256) void attn_kernel(
    const bf16* __restrict__ q, const bf16* __restrict__ k,
    const bf16* __restrict__ v, bf16* __restrict__ o)
{
    __shared__ alignas(16) bf16 sQ[128 * 64];
    __shared__ alignas(16) bf16 sK[2][64 * 64];
    __shared__ alignas(16) bf16 sV[2][64 * 64];
    const int tid  = threadIdx.x;
    const int lane = tid & 63;
    const int w    = tid >> 6;
    const int h    = lane >> 5;
    const int l32  = lane & 31;
    const int qt = blockIdx.x;
    const int bh = blockIdx.y;
    const int b = bh / NH, hh = bh - b * NH;

    const bf16* qb = q + ((size_t)bh * NSEQ + qt * 128) * HD;
    const bf16* kb = k + (size_t)bh * NSEQ * HD;
    const bf16* vb = v + (size_t)bh * HD * NSEQ;

#pragma unroll
    for (int i = 0; i < 4; i++) {
        int slot = w * 256 + i * 64 + lane;
        int r = slot >> 3, cs = slot & 7;
        __builtin_amdgcn_global_load_lds(GLB_CAST(qb + r * HD + ((cs ^ (r & 7)) * 8)),
                                         LDS_CAST(sQ + (w * 256 + i * 64) * 8), 16, 0, 0);
    }
    auto stageKV = [&](int kt, int buf) {
#pragma unroll
        for (int i = 0; i < 2; i++) {
            int slot = w * 128 + i * 64 + lane;
            int r = slot >> 3, cs = slot & 7;
            int cc = (cs ^ (r & 7)) * 8;
            __builtin_amdgcn_global_load_lds(GLB_CAST(kb + (size_t)(kt * 64 + r) * HD + cc),
                                             LDS_CAST(&sK[buf][(w * 128 + i * 64) * 8]), 16, 0, 0);
            __builtin_amdgcn_global_load_lds(GLB_CAST(vb + (size_t)r * NSEQ + kt * 64 + cc),
                                             LDS_CAST(&sV[buf][(w * 128 + i * 64) * 8]), 16, 0, 0);
        }
    };
    stageKV(0, 0);
    __syncthreads();

    bf16x8 qf[4];
    {
        int row = w * 32 + l32, rx = row & 7;
#pragma unroll
        for (int cd = 0; cd < 4; cd++)
            qf[cd] = *(const bf16x8*)(sQ + (row * 8 + ((2 * cd + h) ^ rx)) * 8);
    }

    f32x16 accO[2];
#pragma unroll
    for (int dt = 0; dt < 2; dt++)
#pragma unroll
        for (int i = 0; i < 16; i++) accO[dt][i] = 0.f;
    float m_run = -3e38f, l_run = 0.f;

    for (int kt = 0; kt < 16; kt++) {
        const int cur = kt & 1;
        __syncthreads();
        if (kt < 15) stageKV(kt + 1, 1 - cur);
        const bf16* sKc = sK[cur];
        const bf16* sVc = sV[cur];

        f32x16 accS[2];
#pragma unroll
        for (int kvt = 0; kvt < 2; kvt++)
#pragma unroll
            for (int i = 0; i < 16; i++) accS[kvt][i] = 0.f;
#pragma unroll
        for (int kvt = 0; kvt < 2; kvt++) {
            int row = kvt * 32 + l32, rx = row & 7;
#pragma unroll
            for (int cd = 0; cd < 4; cd++) {
                bf16x8 kf = *(const bf16x8*)(sKc + (row * 8 + ((2 * cd + h) ^ rx)) * 8);
                accS[kvt] = MFMA32(kf, qf[cd], accS[kvt]);
            }
        }

        float tmv[16];
#pragma unroll
        for (int i = 0; i < 16; i++) tmv[i] = fmaxf(accS[0][i], accS[1][i]);
#pragma unroll
        for (int s = 8; s >= 1; s >>= 1)
#pragma unroll
            for (int i = 0; i < s; i++) tmv[i] = fmaxf(tmv[i], tmv[i + s]);
        float tmax = fmaxf(tmv[0], __shfl_xor(tmv[0], 32));
        float mnew = fmaxf(m_run, tmax);
        float alpha = EXPF(m_run - mnew);
        m_run = mnew;

        float tsv[16];
#pragma unroll
        for (int kvt = 0; kvt < 2; kvt++)
#pragma unroll
            for (int i = 0; i < 16; i++) {
                float p = EXPF(accS[kvt][i] - mnew);
                accS[kvt][i] = p;
            }
#pragma unroll
        for (int i = 0; i < 16; i++) tsv[i] = accS[0][i] + accS[1][i];
#pragma unroll
        for (int s = 8; s >= 1; s >>= 1)
#pragma unroll
            for (int i = 0; i < s; i++) tsv[i] += tsv[i + s];
        float rs = tsv[0] + __shfl_xor(tsv[0], 32);
        l_run = l_run * alpha + rs;
#pragma unroll
        for (int dt = 0; dt < 2; dt++)
#pragma unroll
            for (int i = 0; i < 16; i++) accO[dt][i] *= alpha;

        u32 pr[2][4][2];
#pragma unroll
        for (int kvt = 0; kvt < 2; kvt++)
#pragma unroll
            for (int g = 0; g < 4; g++) {
                pr[kvt][g][0] = pkbf(accS[kvt][4 * g + 0], accS[kvt][4 * g + 1]);
                pr[kvt][g][1] = pkbf(accS[kvt][4 * g + 2], accS[kvt][4 * g + 3]);
            }
        bf16x8 pf[4];
#pragma unroll
        for (int c = 0; c < 4; c++) {
            int kvt = c >> 1, c1 = c & 1;
            u32 u00 = pr[kvt][2 * c1][0],     u01 = pr[kvt][2 * c1][1];
            u32 u10 = pr[kvt][2 * c1 + 1][0], u11 = pr[kvt][2 * c1 + 1][1];
            u32 y0 = h ? u10 : u00, y1 = h ? u11 : u01;
            u32 z0 = h ? u00 : u10, z1 = h ? u01 : u11;
            u32 w0 = (u32)__shfl_xor((int)z0, 32);
            u32 w1 = (u32)__shfl_xor((int)z1, 32);
            u32x4 fv = { h ? w0 : y0, h ? w1 : y1, h ? y0 : w0, h ? y1 : w1 };
            pf[c] = __builtin_bit_cast(bf16x8, fv);
        }

#pragma unroll
        for (int dt = 0; dt < 2; dt++) {
            int row = dt * 32 + l32, rx = row & 7;
#pragma unroll
            for (int c = 0; c < 4; c++) {
                bf16x8 vf = *(const bf16x8*)(sVc + (row * 8 + ((2 * c + h) ^ rx)) * 8);
                accO[dt] = MFMA32(vf, pf[c], accO[dt]);
            }
        }
    }

    float inv = 1.f / l_run;
    bf16* ob = o + ((size_t)b * NSEQ + qt * 128 + w * 32 + l32) * CDIM + hh * HD;
#pragma unroll
    for (int dt = 0; dt < 2; dt++)
#pragma unroll
        for (int g = 0; g < 4; g++) {
            bf16x4 t = { (bf16)(accO[dt][4 * g + 0] * inv), (bf16)(accO[dt][4 * g + 1] * inv),
                         (bf16)(accO[dt][4 * g + 2] * inv), (bf16)(accO[dt][4 * g + 3] * inv) };
            *(bf16x4*)(ob + dt * 32 + 8 * g + 4 * h) = t;
        }
}

// ---------------------------------------------------------------
extern "C" void kernel_launch(void* const* d_in, const int* in_sizes, int n_in,
                              void* d_out, int out_size, void* d_ws, size_t ws_size,
                              hipStream_t stream)
{
    const float* x     = (const float*)d_in[0];
    const float* Wqkv  = (const float*)d_in[1];
    const float* bqkv  = (const float*)d_in[2];
    const float* Wproj = (const float*)d_in[3];
    const float* bproj = (const float*)d_in[4];
    float* out = (float*)d_out;

    char* ws = (char*)d_ws;
    const size_t MC2 = (size_t)MTOT * CDIM * 2;
    bf16* xb     = (bf16*)ws; ws += MC2;
    bf16* wqkvt  = (bf16*)ws; ws += (size_t)NC3 * CDIM * 2;
    bf16* wprojt = (bf16*)ws; ws += (size_t)CDIM * CDIM * 2;
    bf16* qw     = (bf16*)ws; ws += MC2;
    bf16* kw     = (bf16*)ws; ws += MC2;
    bf16* vw     = (bf16*)ws; ws += MC2;
    bf16* ow     = (bf16*)ws; ws += MC2;

    int n4 = MTOT * CDIM / 4;
    cast_kernel<<<dim3((n4 + 255) / 256), dim3(256), 0, stream>>>(x, xb, n4);
    tcast_kernel<<<dim3(3, NC3),  dim3(256), 0, stream>>>(Wqkv,  wqkvt,  CDIM, NC3);
    tcast_kernel<<<dim3(3, CDIM), dim3(256), 0, stream>>>(Wproj, wprojt, CDIM, CDIM);

    gemm_kernel<1, 128><<<dim3(NC3 / 128, MTOT / 128), dim3(256), 0, stream>>>(
        xb, wqkvt, bqkv, nullptr, qw, kw, vw, NC3, CDIM);

    attn_kernel<<<dim3(NSEQ / 128, BATCH * NH), dim3(256), 0, stream>>>(qw, kw, vw, ow);

    gemm_kernel<0, 64><<<dim3(CDIM / 128, MTOT / 64), dim3(256), 0, stream>>>(
        ow, wprojt, bproj, out, nullptr, nullptr, nullptr, CDIM, CDIM);
}

// Round 5
// 249.521 us; speedup vs baseline: 1.0022x; 1.0022x over previous
//
#include <hip/hip_runtime.h>
#include <hip/hip_bf16.h>
#include <cstdint>
#include <cstddef>

typedef __bf16 bf16;
typedef __bf16 bf16x8 __attribute__((ext_vector_type(8)));
typedef __bf16 bf16x4 __attribute__((ext_vector_type(4)));
typedef __bf16 bf16x2 __attribute__((ext_vector_type(2)));
typedef float f32x4 __attribute__((ext_vector_type(4)));
typedef float f32x16 __attribute__((ext_vector_type(16)));
typedef unsigned int u32;
typedef u32 u32x4 __attribute__((ext_vector_type(4)));

#define LDS_CAST(p) (__attribute__((address_space(3))) void*)(p)
#define GLB_CAST(p) (const __attribute__((address_space(1))) void*)(p)
#define MFMA32(a, b, c) __builtin_amdgcn_mfma_f32_32x32x16_bf16(a, b, c, 0, 0, 0)

#if __has_builtin(__builtin_amdgcn_exp2f)
#define EXPF(x) __builtin_amdgcn_exp2f(x)
#define QK_SCALE 0.18033688011112042f  /* 0.125 * log2(e) */
#else
#define EXPF(x) __expf(x)
#define QK_SCALE 0.125f
#endif

static constexpr int BATCH = 8;
static constexpr int NSEQ  = 1024;
static constexpr int CDIM  = 768;
static constexpr int NH    = 12;
static constexpr int HD    = 64;
static constexpr int MTOT  = BATCH * NSEQ;   // 8192
static constexpr int NC3   = 3 * CDIM;       // 2304

__device__ inline u32 pkbf(float a, float b) {
    bf16x2 t = { (bf16)a, (bf16)b };
    return __builtin_bit_cast(u32, t);
}

// ---------------- cast fp32 -> bf16 (vectorized) ----------------
__global__ void cast_kernel(const float* __restrict__ src, bf16* __restrict__ dst, int n4) {
    int i = blockIdx.x * blockDim.x + threadIdx.x;
    if (i < n4) {
        float4 v = ((const float4*)src)[i];
        bf16x4 o = { (bf16)v.x, (bf16)v.y, (bf16)v.z, (bf16)v.w };
        ((bf16x4*)dst)[i] = o;
    }
}

// ------------- tiled transpose-cast: dst[n][k] = (bf16)src[k][n] -------------
// 64x64 tile via LDS: coalesced float4 reads, coalesced bf16x8 writes.
__global__ __launch_bounds__(256) void tcast_kernel(
    const float* __restrict__ src, bf16* __restrict__ dst, int K, int N)
{
    __shared__ bf16 sT[64 * 72];            // [n_local][k_local], 144B row stride (16B-aligned)
    const int tid = threadIdx.x;
    const int k0 = blockIdx.x * 64;
    const int n0 = blockIdx.y * 64;
#pragma unroll
    for (int i = 0; i < 4; i++) {
        int slot = tid + i * 256;           // 1024 float4 slots
        int kr = slot >> 4, c4 = slot & 15;
        float4 v = *(const float4*)(src + (size_t)(k0 + kr) * N + n0 + c4 * 4);
        sT[(c4 * 4 + 0) * 72 + kr] = (bf16)v.x;
        sT[(c4 * 4 + 1) * 72 + kr] = (bf16)v.y;
        sT[(c4 * 4 + 2) * 72 + kr] = (bf16)v.z;
        sT[(c4 * 4 + 3) * 72 + kr] = (bf16)v.w;
    }
    __syncthreads();
#pragma unroll
    for (int i = 0; i < 2; i++) {
        int slot = tid + i * 256;           // 512 bf16x8 slots
        int nr = slot >> 3, kc8 = slot & 7;
        *(bf16x8*)(dst + (size_t)(n0 + nr) * K + k0 + kc8 * 8) =
            *(const bf16x8*)(sT + nr * 72 + kc8 * 8);
    }
}

// ---------------- QKV GEMM: 512 thr, 128x128 tile, 8 waves of 64x32 ----------------
// acc = 32 AGPR/wave -> launch_bounds(512,4) => 4 waves/SIMD => 16 waves/CU resident.
// Scatter q/k -> [B,H,N,D] (q pre-scaled), v -> [B,H,D,N].
__global__ __launch_bounds__(512, 4) void gemm_qkv_kernel(
    const bf16* __restrict__ A, const bf16* __restrict__ Bt,
    const float* __restrict__ bias,
    bf16* __restrict__ q, bf16* __restrict__ kk, bf16* __restrict__ v, int K)
{
    __shared__ alignas(16) bf16 sA[2][128 * 32];
    __shared__ alignas(16) bf16 sB[2][128 * 32];
    const int tid  = threadIdx.x;
    const int lane = tid & 63;
    const int w    = tid >> 6;           // 0..7
    const int h    = lane >> 5;
    const int l32  = lane & 31;
    const int wm   = (w >> 2) * 64;      // 2 m-halves
    const int wn   = (w & 3) * 32;       // 4 n-quarters
    const int tm   = blockIdx.y * 128;
    const int tn   = blockIdx.x * 128;

    const bf16* gA = A  + (size_t)tm * K;
    const bf16* gB = Bt + (size_t)tn * K;

    // chunk-major LDS: slot s = c*128 + r holds 16B (row r, k-chunk c); 512 slots, 1 instr each
    const int sr = tid & 127, sc = tid >> 7;
    auto stage = [&](int k0, int buf) {
        __builtin_amdgcn_global_load_lds(GLB_CAST(gA + (size_t)sr * K + k0 + sc * 8),
            LDS_CAST(&sA[buf][w * 512]), 16, 0, 0);
        __builtin_amdgcn_global_load_lds(GLB_CAST(gB + (size_t)sr * K + k0 + sc * 8),
            LDS_CAST(&sB[buf][w * 512]), 16, 0, 0);
    };

    f32x16 acc[2];
#pragma unroll
    for (int t = 0; t < 2; t++)
#pragma unroll
        for (int i = 0; i < 16; i++) acc[t][i] = 0.f;

    const int NK = K / 32;
    stage(0, 0);
    for (int kt = 0; kt < NK; kt++) {
        const int cur = kt & 1;
        __syncthreads();                              // drains cur-buf loads
        if (kt + 1 < NK) stage((kt + 1) * 32, cur ^ 1);  // prefetch overlaps compute
        const bf16* sAc = sA[cur];
        const bf16* sBc = sB[cur];

        bf16x8 af[2][2], bfr[2];
#pragma unroll
        for (int t = 0; t < 2; t++)
#pragma unroll
            for (int kc = 0; kc < 2; kc++)
                af[t][kc] = *(const bf16x8*)(sAc + ((kc * 2 + h) * 128 + wm + t * 32 + l32) * 8);
#pragma unroll
        for (int kc = 0; kc < 2; kc++)
            bfr[kc] = *(const bf16x8*)(sBc + ((kc * 2 + h) * 128 + wn + l32) * 8);
#pragma unroll
        for (int kc = 0; kc < 2; kc++)
#pragma unroll
            for (int t = 0; t < 2; t++)
                acc[t] = MFMA32(af[t][kc], bfr[kc], acc[t]);
    }

    // C/D 32x32: col = l32, row_local = (r&3) + 8*(r>>2) + 4*h
    const int region = tn / 768;                  // 0=q, 1=k, 2=v (uniform per block)
    const int rem = tn - region * 768 + wn + l32;
    const int hd = rem >> 6, d = rem & 63;
    const float bv = bias[region * 768 + rem];
#pragma unroll
    for (int t = 0; t < 2; t++) {
        int mrow = tm + wm + t * 32 + 4 * h;
        int b   = mrow >> 10;
        int nsb = mrow & 1023;
        if (region == 2) {
            bf16* vp = v + ((size_t)(b * NH + hd) * HD + d) * NSEQ + nsb;
#pragma unroll
            for (int g = 0; g < 4; g++) {
                bf16x4 t4 = { (bf16)(acc[t][4 * g + 0] + bv), (bf16)(acc[t][4 * g + 1] + bv),
                              (bf16)(acc[t][4 * g + 2] + bv), (bf16)(acc[t][4 * g + 3] + bv) };
                *(bf16x4*)(vp + 8 * g) = t4;
            }
        } else {
            bf16* qp = (region == 0 ? q : kk) + ((size_t)(b * NH + hd) * NSEQ + nsb) * HD + d;
            const float sc2 = (region == 0) ? (float)QK_SCALE : 1.0f;
#pragma unroll
            for (int r = 0; r < 16; r++) {
                int rl = (r & 3) + 8 * (r >> 2);
                qp[(size_t)rl * HD] = (bf16)((acc[t][r] + bv) * sc2);
            }
        }
    }
}

// ---------------- proj GEMM: 256 thr, 64x128 tile, 4 waves of 64x32, fp32 out ----------------
__global__ __launch_bounds__(256, 4) void gemm_proj_kernel(
    const bf16* __restrict__ A, const bf16* __restrict__ Bt,
    const float* __restrict__ bias, float* __restrict__ outf, int Ndim, int K)
{
    constexpr int TM = 64;
    __shared__ alignas(16) bf16 sA[2][TM * 32];
    __shared__ alignas(16) bf16 sB[2][128 * 32];
    const int tid  = threadIdx.x;
    const int lane = tid & 63;
    const int w    = tid >> 6;
    const int h    = lane >> 5;
    const int l32  = lane & 31;
    const int wn   = w * 32;
    const int tm   = blockIdx.y * TM;
    const int tn   = blockIdx.x * 128;

    const bf16* gA = A  + (size_t)tm * K;
    const bf16* gB = Bt + (size_t)tn * K;

    auto stage = [&](int k0, int buf) {
        {
            int s = w * 64 + lane;                 // 256 A slots
            int r = s % TM, c = s / TM;
            __builtin_amdgcn_global_load_lds(GLB_CAST(gA + (size_t)r * K + k0 + c * 8),
                LDS_CAST(&sA[buf][w * 512]), 16, 0, 0);
        }
#pragma unroll
        for (int i = 0; i < 2; i++) {
            int s = (w * 2 + i) * 64 + lane;       // 512 B slots
            int r = s & 127, c = s >> 7;
            __builtin_amdgcn_global_load_lds(GLB_CAST(gB + (size_t)r * K + k0 + c * 8),
                LDS_CAST(&sB[buf][(w * 2 + i) * 512]), 16, 0, 0);
        }
    };

    f32x16 acc[2];
#pragma unroll
    for (int t = 0; t < 2; t++)
#pragma unroll
        for (int i = 0; i < 16; i++) acc[t][i] = 0.f;

    const int NK = K / 32;
    stage(0, 0);
    for (int kt = 0; kt < NK; kt++) {
        const int cur = kt & 1;
        __syncthreads();
        if (kt + 1 < NK) stage((kt + 1) * 32, cur ^ 1);
        const bf16* sAc = sA[cur];
        const bf16* sBc = sB[cur];

        bf16x8 af[2][2], bfr[2];
#pragma unroll
        for (int t = 0; t < 2; t++)
#pragma unroll
            for (int kc = 0; kc < 2; kc++)
                af[t][kc] = *(const bf16x8*)(sAc + ((kc * 2 + h) * TM + t * 32 + l32) * 8);
#pragma unroll
        for (int kc = 0; kc < 2; kc++)
            bfr[kc] = *(const bf16x8*)(sBc + ((kc * 2 + h) * 128 + wn + l32) * 8);
#pragma unroll
        for (int kc = 0; kc < 2; kc++)
#pragma unroll
            for (int t = 0; t < 2; t++)
                acc[t] = MFMA32(af[t][kc], bfr[kc], acc[t]);
    }

    const int col = tn + wn + l32;
    const float bv = bias[col];
#pragma unroll
    for (int t = 0; t < 2; t++) {
        int mrow = tm + t * 32 + 4 * h;
        float* op = outf + (size_t)mrow * Ndim + col;
#pragma unroll
        for (int r = 0; r < 16; r++) {
            int rl = (r & 3) + 8 * (r >> 2);
            op[(size_t)rl * Ndim] = acc[t][r] + bv;
        }
    }
}

// ---------------- flash attention: S^T/O^T formulation, 32x32 MFMA (unchanged) ----------------
__global__ __launch_bounds__(256) void attn_kernel(
    const bf16* __restrict__ q, const bf16* __restrict__ k,
    const bf16* __restrict__ v, bf16* __restrict__ o)
{
    __shared__ alignas(16) bf16 sQ[128 * 64];
    __shared__ alignas(16) bf16 sK[2][64 * 64];
    __shared__ alignas(16) bf16 sV[2][64 * 64];
    const int tid  = threadIdx.x;
    const int lane = tid & 63;
    const int w    = tid >> 6;
    const int h    = lane >> 5;
    const int l32  = lane & 31;
    const int qt = blockIdx.x;
    const int bh = blockIdx.y;
    const int b = bh / NH, hh = bh - b * NH;

    const bf16* qb = q + ((size_t)bh * NSEQ + qt * 128) * HD;
    const bf16* kb = k + (size_t)bh * NSEQ * HD;
    const bf16* vb = v + (size_t)bh * HD * NSEQ;

#pragma unroll
    for (int i = 0; i < 4; i++) {
        int slot = w * 256 + i * 64 + lane;
        int r = slot >> 3, cs = slot & 7;
        __builtin_amdgcn_global_load_lds(GLB_CAST(qb + r * HD + ((cs ^ (r & 7)) * 8)),
                                         LDS_CAST(sQ + (w * 256 + i * 64) * 8), 16, 0, 0);
    }
    auto stageKV = [&](int kt, int buf) {
#pragma unroll
        for (int i = 0; i < 2; i++) {
            int slot = w * 128 + i * 64 + lane;
            int r = slot >> 3, cs = slot & 7;
            int cc = (cs ^ (r & 7)) * 8;
            __builtin_amdgcn_global_load_lds(GLB_CAST(kb + (size_t)(kt * 64 + r) * HD + cc),
                                             LDS_CAST(&sK[buf][(w * 128 + i * 64) * 8]), 16, 0, 0);
            __builtin_amdgcn_global_load_lds(GLB_CAST(vb + (size_t)r * NSEQ + kt * 64 + cc),
                                             LDS_CAST(&sV[buf][(w * 128 + i * 64) * 8]), 16, 0, 0);
        }
    };
    stageKV(0, 0);
    __syncthreads();

    bf16x8 qf[4];
    {
        int row = w * 32 + l32, rx = row & 7;
#pragma unroll
        for (int cd = 0; cd < 4; cd++)
            qf[cd] = *(const bf16x8*)(sQ + (row * 8 + ((2 * cd + h) ^ rx)) * 8);
    }

    f32x16 accO[2];
#pragma unroll
    for (int dt = 0; dt < 2; dt++)
#pragma unroll
        for (int i = 0; i < 16; i++) accO[dt][i] = 0.f;
    float m_run = -3e38f, l_run = 0.f;

    for (int kt = 0; kt < 16; kt++) {
        const int cur = kt & 1;
        __syncthreads();
        if (kt < 15) stageKV(kt + 1, 1 - cur);
        const bf16* sKc = sK[cur];
        const bf16* sVc = sV[cur];

        f32x16 accS[2];
#pragma unroll
        for (int kvt = 0; kvt < 2; kvt++)
#pragma unroll
            for (int i = 0; i < 16; i++) accS[kvt][i] = 0.f;
#pragma unroll
        for (int kvt = 0; kvt < 2; kvt++) {
            int row = kvt * 32 + l32, rx = row & 7;
#pragma unroll
            for (int cd = 0; cd < 4; cd++) {
                bf16x8 kf = *(const bf16x8*)(sKc + (row * 8 + ((2 * cd + h) ^ rx)) * 8);
                accS[kvt] = MFMA32(kf, qf[cd], accS[kvt]);
            }
        }

        float tmv[16];
#pragma unroll
        for (int i = 0; i < 16; i++) tmv[i] = fmaxf(accS[0][i], accS[1][i]);
#pragma unroll
        for (int s = 8; s >= 1; s >>= 1)
#pragma unroll
            for (int i = 0; i < s; i++) tmv[i] = fmaxf(tmv[i], tmv[i + s]);
        float tmax = fmaxf(tmv[0], __shfl_xor(tmv[0], 32));
        float mnew = fmaxf(m_run, tmax);
        float alpha = EXPF(m_run - mnew);
        m_run = mnew;

        float tsv[16];
#pragma unroll
        for (int kvt = 0; kvt < 2; kvt++)
#pragma unroll
            for (int i = 0; i < 16; i++) {
                float p = EXPF(accS[kvt][i] - mnew);
                accS[kvt][i] = p;
            }
#pragma unroll
        for (int i = 0; i < 16; i++) tsv[i] = accS[0][i] + accS[1][i];
#pragma unroll
        for (int s = 8; s >= 1; s >>= 1)
#pragma unroll
            for (int i = 0; i < s; i++) tsv[i] += tsv[i + s];
        float rs = tsv[0] + __shfl_xor(tsv[0], 32);
        l_run = l_run * alpha + rs;
#pragma unroll
        for (int dt = 0; dt < 2; dt++)
#pragma unroll
            for (int i = 0; i < 16; i++) accO[dt][i] *= alpha;

        u32 pr[2][4][2];
#pragma unroll
        for (int kvt = 0; kvt < 2; kvt++)
#pragma unroll
            for (int g = 0; g < 4; g++) {
                pr[kvt][g][0] = pkbf(accS[kvt][4 * g + 0], accS[kvt][4 * g + 1]);
                pr[kvt][g][1] = pkbf(accS[kvt][4 * g + 2], accS[kvt][4 * g + 3]);
            }
        bf16x8 pf[4];
#pragma unroll
        for (int c = 0; c < 4; c++) {
            int kvt = c >> 1, c1 = c & 1;
            u32 u00 = pr[kvt][2 * c1][0],     u01 = pr[kvt][2 * c1][1];
            u32 u10 = pr[kvt][2 * c1 + 1][0], u11 = pr[kvt][2 * c1 + 1][1];
            u32 y0 = h ? u10 : u00, y1 = h ? u11 : u01;
            u32 z0 = h ? u00 : u10, z1 = h ? u01 : u11;
            u32 w0 = (u32)__shfl_xor((int)z0, 32);
            u32 w1 = (u32)__shfl_xor((int)z1, 32);
            u32x4 fv = { h ? w0 : y0, h ? w1 : y1, h ? y0 : w0, h ? y1 : w1 };
            pf[c] = __builtin_bit_cast(bf16x8, fv);
        }

#pragma unroll
        for (int dt = 0; dt < 2; dt++) {
            int row = dt * 32 + l32, rx = row & 7;
#pragma unroll
            for (int c = 0; c < 4; c++) {
                bf16x8 vf = *(const bf16x8*)(sVc + (row * 8 + ((2 * c + h) ^ rx)) * 8);
                accO[dt] = MFMA32(vf, pf[c], accO[dt]);
            }
        }
    }

    float inv = 1.f / l_run;
    bf16* ob = o + ((size_t)b * NSEQ + qt * 128 + w * 32 + l32) * CDIM + hh * HD;
#pragma unroll
    for (int dt = 0; dt < 2; dt++)
#pragma unroll
        for (int g = 0; g < 4; g++) {
            bf16x4 t = { (bf16)(accO[dt][4 * g + 0] * inv), (bf16)(accO[dt][4 * g + 1] * inv),
                         (bf16)(accO[dt][4 * g + 2] * inv), (bf16)(accO[dt][4 * g + 3] * inv) };
            *(bf16x4*)(ob + dt * 32 + 8 * g + 4 * h) = t;
        }
}

// ---------------------------------------------------------------
extern "C" void kernel_launch(void* const* d_in, const int* in_sizes, int n_in,
                              void* d_out, int out_size, void* d_ws, size_t ws_size,
                              hipStream_t stream)
{
    const float* x     = (const float*)d_in[0];
    const float* Wqkv  = (const float*)d_in[1];
    const float* bqkv  = (const float*)d_in[2];
    const float* Wproj = (const float*)d_in[3];
    const float* bproj = (const float*)d_in[4];
    float* out = (float*)d_out;

    char* ws = (char*)d_ws;
    const size_t MC2 = (size_t)MTOT * CDIM * 2;
    bf16* xb     = (bf16*)ws; ws += MC2;
    bf16* wqkvt  = (bf16*)ws; ws += (size_t)NC3 * CDIM * 2;
    bf16* wprojt = (bf16*)ws; ws += (size_t)CDIM * CDIM * 2;
    bf16* qw     = (bf16*)ws; ws += MC2;
    bf16* kw     = (bf16*)ws; ws += MC2;
    bf16* vw     = (bf16*)ws; ws += MC2;
    bf16* ow     = (bf16*)ws; ws += MC2;

    int n4 = MTOT * CDIM / 4;
    cast_kernel<<<dim3((n4 + 255) / 256), dim3(256), 0, stream>>>(x, xb, n4);
    tcast_kernel<<<dim3(CDIM / 64, NC3 / 64),  dim3(256), 0, stream>>>(Wqkv,  wqkvt,  CDIM, NC3);
    tcast_kernel<<<dim3(CDIM / 64, CDIM / 64), dim3(256), 0, stream>>>(Wproj, wprojt, CDIM, CDIM);

    gemm_qkv_kernel<<<dim3(NC3 / 128, MTOT / 128), dim3(512), 0, stream>>>(
        xb, wqkvt, bqkv, qw, kw, vw, CDIM);

    attn_kernel<<<dim3(NSEQ / 128, BATCH * NH), dim3(256), 0, stream>>>(qw, kw, vw, ow);

    gemm_proj_kernel<<<dim3(CDIM / 128, MTOT / 64), dim3(256), 0, stream>>>(
        ow, wprojt, bproj, out, CDIM, CDIM);
}